// Round 4
// baseline (42.997 us; speedup 1.0000x reference)
//
#include <hip/hip_runtime.h>

#define NCLS   80
#define NA     9
#define NH     64
#define NW     64
#define NB     8
#define NGT    32
#define NANCH  (NA * NH * NW)            // 36864 anchors per image
#define BLK_A  128                       // anchors per BCE block
#define NTHR   256
#define NBLK1  (NB * NANCH / NTHR)       // 1152 assign blocks
#define NBLK2  (NB * NANCH / BLK_A)      // 2304 BCE blocks
#define B1_PER_IMG (NANCH / NTHR)        // 144
#define B2_PER_IMG (NANCH / BLK_A)       // 288
#define KI     10                        // float4 logit loads per BCE thread

// ws layout: ints flags[294912]; then floats: PLX[1152], PPC[1152], PLC[2304]
#define NANCH_ALL (NB * NANCH)
#define PLX 0
#define PPC NBLK1
#define PLC (2 * NBLK1)

// Anchor W/H computed in double (matches Python float arithmetic), cast to f32.
__device__ __constant__ float c_aw[9] = {
    (float)(32.0 * 1.0    * 1.0), (float)(32.0 * 1.0    * 1.4), (float)(32.0 * 1.0    * 0.7),
    (float)(32.0 * 1.2599 * 1.0), (float)(32.0 * 1.2599 * 1.4), (float)(32.0 * 1.2599 * 0.7),
    (float)(32.0 * 1.5874 * 1.0), (float)(32.0 * 1.5874 * 1.4), (float)(32.0 * 1.5874 * 0.7)};
__device__ __constant__ float c_ah[9] = {
    (float)(32.0 * 1.0    * 1.0), (float)(32.0 * 1.0    * 0.7), (float)(32.0 * 1.0    * 1.4),
    (float)(32.0 * 1.2599 * 1.0), (float)(32.0 * 1.2599 * 0.7), (float)(32.0 * 1.2599 * 1.4),
    (float)(32.0 * 1.5874 * 1.0), (float)(32.0 * 1.5874 * 0.7), (float)(32.0 * 1.5874 * 1.4)};

// ---- Kernel 1: anchor assignment (IoU, flags, xywh loss partials) ----
__global__ __launch_bounds__(NTHR) void retina_assign(
    const float* __restrict__ t_xywh,      // [B, N, 4]
    const float* __restrict__ gt_bboxes,   // [B, 32, 4] cxcywh
    const int*   __restrict__ gt_cats,     // [B, 32]
    int*   __restrict__ flags,             // [B*N]
    float* __restrict__ part)
{
    __shared__ float4 s_gt[NGT];
    __shared__ int    s_cat[NGT];
    __shared__ float  s_red[4 * 2];

    const int tid = threadIdx.x;
    const int blk = blockIdx.x;
    const int b   = blk / B1_PER_IMG;
    const int n   = (blk % B1_PER_IMG) * NTHR + tid;   // anchor within image
    const int g   = blk * NTHR + tid;                  // global anchor == b*NANCH+n

    if (tid < NGT) {
        s_gt[tid]  = ((const float4*)gt_bboxes)[b * NGT + tid];
        s_cat[tid] = gt_cats[b * NGT + tid];
    }
    __syncthreads();

    const int a  = n >> 12;
    const int hy = (n >> 6) & 63;
    const int wx = n & 63;
    const float acx = (wx + 0.5f) * 8.0f;
    const float acy = (hy + 0.5f) * 8.0f;
    const float aw  = c_aw[a];
    const float ah  = c_ah[a];

    // ---- IoU vs 32 GTs, bit-exact op order vs numpy reference ----
    float best = -1.0f;
    int   bi   = 0;
    {
#pragma clang fp contract(off)
        const float a_tlx = acx - aw * 0.5f, a_tly = acy - ah * 0.5f;
        const float a_brx = acx + aw * 0.5f, a_bry = acy + ah * 0.5f;
        const float area_a = aw * ah;
        for (int gg = 0; gg < NGT; ++gg) {
            const float4 gb = s_gt[gg];
            const float g_tlx = gb.x - gb.z * 0.5f, g_tly = gb.y - gb.w * 0.5f;
            const float g_brx = gb.x + gb.z * 0.5f, g_bry = gb.y + gb.w * 0.5f;
            float dx = fminf(a_brx, g_brx) - fmaxf(a_tlx, g_tlx);
            float dy = fminf(a_bry, g_bry) - fmaxf(a_tly, g_tly);
            dx = fmaxf(dx, 0.0f);
            dy = fmaxf(dy, 0.0f);
            const float inter = dx * dy;
            const float area_g = gb.z * gb.w;
            const float uni  = area_a + area_g - inter;   // no fma
            const float iou  = inter / uni;
            if (iou > best) { best = iou; bi = gg; }      // strict > = first argmax
        }
    }

    const bool pos = best > 0.5f;
    const bool neg = best < 0.4f;
    flags[g] = (pos | neg) ? (pos ? s_cat[bi] : 256) : -1;

    float lx = 0.0f, pcnt = 0.0f;
    if (pos) {
        pcnt = 1.0f;
        const float4 gt = s_gt[bi];
        const float4 t  = ((const float4*)t_xywh)[g];
        const float tx = (gt.x - acx) / aw;
        const float ty = (gt.y - acy) / ah;
        const float tw = logf(gt.z / aw + 1e-8f);
        const float th = logf(gt.w / ah + 1e-8f);
        const float d0 = t.x - tx, d1 = t.y - ty, d2 = t.z - tw, d3 = t.w - th;
        lx = d0 * d0 + d1 * d1 + d2 * d2 + d3 * d3;
    }

    float v1 = lx, v2 = pcnt;
    for (int o = 32; o > 0; o >>= 1) {
        v1 += __shfl_down(v1, o);
        v2 += __shfl_down(v2, o);
    }
    const int wave = tid >> 6;
    if ((tid & 63) == 0) {
        s_red[wave * 2 + 0] = v1;
        s_red[wave * 2 + 1] = v2;
    }
    __syncthreads();
    if (tid == 0) {
        float xw = 0.0f, pc = 0.0f;
        for (int w2 = 0; w2 < 4; ++w2) { xw += s_red[w2 * 2]; pc += s_red[w2 * 2 + 1]; }
        part[PLX + blk] = xw;
        part[PPC + blk] = pc;
    }
}

// ---- Kernel 2: pure streaming BCE over logits ----
__global__ __launch_bounds__(NTHR) void retina_bce(
    const float* __restrict__ cls_logits,  // [B, N, 80]
    const int*   __restrict__ flags,       // [B*N]
    float* __restrict__ part)
{
    __shared__ int   s_flag[BLK_A];
    __shared__ float s_red[4];

    const int tid = threadIdx.x;
    const int blk = blockIdx.x;

    // issue all streaming loads immediately
    const float4* base = (const float4*)cls_logits + (size_t)blk * (BLK_A * NCLS / 4);
    float4 xb[KI];
#pragma unroll
    for (int k = 0; k < KI; ++k) xb[k] = base[k * NTHR + tid];

    if (tid < BLK_A) s_flag[tid] = flags[blk * BLK_A + tid];
    __syncthreads();

    float lc = 0.0f;
#pragma unroll
    for (int k = 0; k < KI; ++k) {
        const int e  = k * NTHR + tid;       // float4 index within block chunk
        const int la = e / 20;               // local anchor (20 f4 per anchor)
        const int c0 = (e - la * 20) * 4;    // starting class of this f4
        const float4 x = xb[k];
        const int f = s_flag[la];
        if (f >= 0) {
            const float xs[4] = {x.x, x.y, x.z, x.w};
#pragma unroll
            for (int j = 0; j < 4; ++j) {
                const float xv = xs[j];
                float sp = fmaxf(xv, 0.0f) + __logf(1.0f + __expf(-fabsf(xv)));
                if (c0 + j == f) sp -= xv;   // one-hot target at positive anchor
                lc += sp;
            }
        }
    }

    float v0 = lc;
    for (int o = 32; o > 0; o >>= 1) v0 += __shfl_down(v0, o);
    if ((tid & 63) == 0) s_red[tid >> 6] = v0;
    __syncthreads();
    if (tid == 0)
        part[PLC + blk] = s_red[0] + s_red[1] + s_red[2] + s_red[3];
}

// ---- Kernel 3: fold partials into the scalar loss ----
__global__ __launch_bounds__(256) void retina_final(
    const float* __restrict__ part, float* __restrict__ out)
{
    __shared__ float s_lc[NB], s_pc[NB], s_lx[4];
    const int tid = threadIdx.x;

    const int b = tid >> 5, l = tid & 31;   // 32 lanes per image
    float lc = 0.0f, pc = 0.0f;
    for (int i = l; i < B2_PER_IMG; i += 32) lc += part[PLC + b * B2_PER_IMG + i];
    for (int i = l; i < B1_PER_IMG; i += 32) pc += part[PPC + b * B1_PER_IMG + i];
    for (int o = 16; o > 0; o >>= 1) {      // xor butterfly stays within the 32-group
        lc += __shfl_xor(lc, o);
        pc += __shfl_xor(pc, o);
    }
    if (l == 0) { s_lc[b] = lc; s_pc[b] = pc; }

    float lxs = 0.0f;
    for (int i = tid; i < NBLK1; i += 256) lxs += part[PLX + i];
    for (int o = 32; o > 0; o >>= 1) lxs += __shfl_down(lxs, o);
    if ((tid & 63) == 0) s_lx[tid >> 6] = lxs;
    __syncthreads();

    if (tid == 0) {
        const float lxt = s_lx[0] + s_lx[1] + s_lx[2] + s_lx[3];
        float s = 0.0f;
        for (int bb = 0; bb < NB; ++bb)
            s += s_lc[bb] / (s_pc[bb] + 1.0f);
        out[0] = (lxt + s) / (float)NB;
    }
}

extern "C" void kernel_launch(void* const* d_in, const int* in_sizes, int n_in,
                              void* d_out, int out_size, void* d_ws, size_t ws_size,
                              hipStream_t stream)
{
    const float* t_xywh     = (const float*)d_in[0];
    const float* cls_logits = (const float*)d_in[1];
    const float* gt_bboxes  = (const float*)d_in[2];
    const int*   gt_cats    = (const int*)d_in[3];

    int*   flags = (int*)d_ws;                     // 294912 ints (1.18 MB)
    float* part  = (float*)d_ws + NANCH_ALL;       // 2*1152 + 2304 floats

    retina_assign<<<NBLK1, NTHR, 0, stream>>>(t_xywh, gt_bboxes, gt_cats, flags, part);
    retina_bce   <<<NBLK2, NTHR, 0, stream>>>(cls_logits, flags, part);
    retina_final <<<1, 256, 0, stream>>>(part, (float*)d_out);
}